// Round 12
// baseline (264.104 us; speedup 1.0000x reference)
//
#include <hip/hip_runtime.h>
#include <math.h>

namespace {
constexpr int Tn = 128, Bn = 16, An = 32, OBS = 256, Kh = 3, NACT = 9, HID = 32;
constexpr int TBA = Tn * Bn * An;   // 65536 rows through the MLP
constexpr int BA  = Bn * An;        // 512 LSTM sequences
constexpr int OUT_LP  = TBA * Kh;         // 196608: logprobs start
constexpr int OUT_ENT = TBA * Kh + TBA;   // 262144: entropies start
constexpr int NCHUNK = 32;                // time-chunks per row (done-reset cuts)
constexpr int CHUNKW = Tn / NCHUNK;       // nominal chunk width (4)

typedef __fp16   pk16x2 __attribute__((ext_vector_type(2)));  // builtin-compatible
typedef _Float16 half8v __attribute__((ext_vector_type(8)));
typedef float    f32x4  __attribute__((ext_vector_type(4)));
}

__device__ __forceinline__ float fast_sig(float x) {
  return __builtin_amdgcn_rcpf(1.f + __expf(-x));
}
__device__ __forceinline__ float fast_tanh(float x) {   // 2*sig(2x)-1, saturates safely
  return fmaf(2.f, fast_sig(2.f * x), -1.f);
}
__device__ __forceinline__ unsigned h2bits(pk16x2 h) {
  return __builtin_bit_cast(unsigned, h);
}
__device__ __forceinline__ pk16x2 bits2h(unsigned u) {
  return __builtin_bit_cast(pk16x2, u);
}
// first set bit index >= n in the 128-bit mask {dm0, dm1}; 128 if none.
__device__ __forceinline__ int first_done_ge(unsigned long long dm0,
                                             unsigned long long dm1, int n) {
  unsigned long long m0 = (n < 64) ? (dm0 & (~0ull << n)) : 0ull;
  unsigned long long m1 = (n < 64) ? dm1 : (dm1 & (~0ull << (n - 64)));
  if (m0) return __builtin_ctzll(m0);
  if (m1) return 64 + __builtin_ctzll(m1);
  return 128;
}
// 3-bucket helpers (runtime bucket index km, no arrays -> no scratch)
__device__ __forceinline__ void bmax3(float& m0, float& m1, float& m2,
                                      int km, float v) {
  m0 = (km == 0) ? fmaxf(m0, v) : m0;
  m1 = (km == 1) ? fmaxf(m1, v) : m1;
  m2 = (km == 2) ? fmaxf(m2, v) : m2;
}
__device__ __forceinline__ void badd3(float& s0, float& s1, float& s2,
                                      int km, float v) {
  s0 += (km == 0) ? v : 0.f;
  s1 += (km == 1) ? v : 0.f;
  s2 += (km == 2) ? v : 0.f;
}
__device__ __forceinline__ float bsel3(float x0, float x1, float x2, int km) {
  return (km == 0) ? x0 : ((km == 1) ? x1 : x2);
}
__device__ __forceinline__ int bseli3(int x0, int x1, int x2, int km) {
  return (km == 0) ? x0 : ((km == 1) ? x1 : x2);
}

// fp32 global -> fp16 B-fragment (8 consecutive weights of row o). Same cast
// and same values the old LDS path produced -> bit-identical MFMA inputs.
__device__ __forceinline__ half8v wfrag(const float* __restrict__ Wg,
                                        int stride, int o, int kbase) {
  const float* p = &Wg[(size_t)o*stride + kbase];
  float4 c0 = *(const float4*)p;
  float4 c1 = *(const float4*)(p + 4);
  return (half8v){(_Float16)c0.x, (_Float16)c0.y, (_Float16)c0.z, (_Float16)c0.w,
                  (_Float16)c1.x, (_Float16)c1.y, (_Float16)c1.z, (_Float16)c1.w};
}

// ---------------------------------------------------------------------------
// MLP v8: BARRIER-FREE. The B-fragment addresses are wave-independent, so
// weights go global->register per wave (L1-hot: all 8 waves read the same
// 32KB slab; first wave warms it from L2). No wt LDS, no stage, and since
// act is wave-private (proven in v5's z hand-off), ZERO __syncthreads.
// The phase chain stage->vmcnt(0)drain->barrier that pinned every prior
// variant at ~41us is gone; waves run free, TLP hides L1/L2 latency.
// MFMA order and all casts identical to v5 -> bit-identical output.
// LDS 34.8 KB (act only). Cost: redundant per-wave f32->f16 cvt (~1us/CU
// aggregate VALU), cheap vs the 41us barrier serialization it removes.
// ---------------------------------------------------------------------------
__global__ __launch_bounds__(512, 4) void mlp_kernel(
    const float* __restrict__ x,
    const float* __restrict__ W1, const float* __restrict__ W2,
    const float* __restrict__ W3, const float* __restrict__ Wih,
    const float* __restrict__ b1, const float* __restrict__ b2,
    const float* __restrict__ b3, const float* __restrict__ bih,
    const float* __restrict__ bhh, uint2* __restrict__ G1q)
{
  __shared__ __align__(16) _Float16 act[128*136];  // activations (wave-private rows)
  const int tid  = threadIdx.x;                // 0..511
  const int w    = tid >> 6;                   // 0..7
  const int lane = tid & 63;
  const int ln   = lane & 15;
  const int quad = lane >> 4;
  const int rA   = 16*w + ln;                  // 0..127
  const int r0   = 16*w + quad*4;
  const int R0   = blockIdx.x * 128;
  f32x4 acc[8];
  const float* xrow = &x[(size_t)(R0 + rA)*OBS + quad*8];

#define XLOAD(KT, U0, U1, U2, U3) {                                   \
    const float* xp_ = xrow + (KT)*64;                                \
    U0 = *(const float4*)(xp_);      U1 = *(const float4*)(xp_ + 4);  \
    U2 = *(const float4*)(xp_ + 32); U3 = *(const float4*)(xp_ + 36); }
#define XCVT(U0, U1, U2, U3, A0, A1) {                                         \
    A0 = (half8v){(_Float16)U0.x,(_Float16)U0.y,(_Float16)U0.z,(_Float16)U0.w, \
                  (_Float16)U1.x,(_Float16)U1.y,(_Float16)U1.z,(_Float16)U1.w};\
    A1 = (half8v){(_Float16)U2.x,(_Float16)U2.y,(_Float16)U2.z,(_Float16)U2.w, \
                  (_Float16)U3.x,(_Float16)U3.y,(_Float16)U3.z,(_Float16)U3.w}; }

  // reg-A x slab against global-B weight frags; kc0 (all oc) then kc1 --
  // same accumulation order as v5's mfma_regA.
#define MM_REGA(NOC, WG, WSTR, KB, A0, A1)                                  \
  _Pragma("unroll") for (int oc = 0; oc < (NOC); ++oc) {                    \
    half8v b_ = wfrag(WG, WSTR, oc*16 + ln, (KB) + quad*8);                 \
    acc[oc] = __builtin_amdgcn_mfma_f32_16x16x32_f16(A0, b_, acc[oc],0,0,0);\
  }                                                                         \
  _Pragma("unroll") for (int oc = 0; oc < (NOC); ++oc) {                    \
    half8v b_ = wfrag(WG, WSTR, oc*16 + ln, (KB) + 32 + quad*8);            \
    acc[oc] = __builtin_amdgcn_mfma_f32_16x16x32_f16(A1, b_, acc[oc],0,0,0);\
  }

  // LDS-A act slab against global-B weight frags; kc-outer like mfma_slab.
#define MM_ACT(NOC, WG, WSTR, KB)                                              \
  _Pragma("unroll") for (int kc = 0; kc < 2; ++kc) {                           \
    half8v a_ = *(const half8v*)&act[rA*136 + (KB) + kc*32 + quad*8];          \
    _Pragma("unroll") for (int oc = 0; oc < (NOC); ++oc) {                     \
      half8v b_ = wfrag(WG, WSTR, oc*16 + ln, (KB) + kc*32 + quad*8);          \
      acc[oc] = __builtin_amdgcn_mfma_f32_16x16x32_f16(a_, b_, acc[oc],0,0,0); \
    }                                                                          \
  }

  float4 u0, u1, u2, u3, v0, v1, v2, v3;
  half8v a0, a1;

  // ---- layer 1: 256 -> 128 (x in registers, 1-ahead; no barriers) ----
#pragma unroll
  for (int oc = 0; oc < 8; ++oc) acc[oc] = (f32x4)0.f;
  XLOAD(0, u0, u1, u2, u3);
  XLOAD(1, v0, v1, v2, v3);
  XCVT(u0, u1, u2, u3, a0, a1);
  MM_REGA(8, W1, 256, 0, a0, a1)
  XLOAD(2, u0, u1, u2, u3);
  XCVT(v0, v1, v2, v3, a0, a1);
  MM_REGA(8, W1, 256, 64, a0, a1)
  XLOAD(3, v0, v1, v2, v3);
  XCVT(u0, u1, u2, u3, a0, a1);
  MM_REGA(8, W1, 256, 128, a0, a1)
  XCVT(v0, v1, v2, v3, a0, a1);
  MM_REGA(8, W1, 256, 192, a0, a1)

  // L1 epilogue (wave-private act rows)
#pragma unroll
  for (int oc = 0; oc < 8; ++oc) {
    int o = oc*16 + ln;
    float bv = b1[o];
#pragma unroll
    for (int r = 0; r < 4; ++r)
      act[(r0 + r)*136 + o] = (_Float16)fast_tanh(acc[oc][r] + bv);
  }

  // ---- layer 2: 128 -> 128 ----
#pragma unroll
  for (int oc = 0; oc < 8; ++oc) acc[oc] = (f32x4)0.f;
  MM_ACT(8, W2, 128, 0)
  MM_ACT(8, W2, 128, 64)
#pragma unroll
  for (int oc = 0; oc < 8; ++oc) {
    int o = oc*16 + ln;
    float bv = b2[o];
#pragma unroll
    for (int r = 0; r < 4; ++r)
      act[(r0 + r)*136 + o] = (_Float16)fast_tanh(acc[oc][r] + bv);
  }

  // ---- layer 3: 128 -> 64 ----
#pragma unroll
  for (int oc = 0; oc < 4; ++oc) acc[oc] = (f32x4)0.f;
  MM_ACT(4, W3, 128, 0)
  MM_ACT(4, W3, 128, 64)
  // z -> act cols 0..63 (wave-private)
#pragma unroll
  for (int oc = 0; oc < 4; ++oc) {
    int o = oc*16 + ln;
    float bv = b3[o];
#pragma unroll
    for (int r = 0; r < 4; ++r)
      act[(r0 + r)*136 + o] = (_Float16)(acc[oc][r] + bv);
  }

  // ---- layer 4: z(64) -> 128 gate inputs ----
#pragma unroll
  for (int oc = 0; oc < 8; ++oc) acc[oc] = (f32x4)0.f;
  MM_ACT(8, Wih, 64, 0)
#pragma unroll
  for (int p = 0; p < 2; ++p) {
    int ui = p*16 + ln;
    float bi = bih[ui]      + bhh[ui];
    float bf = bih[ui + 32] + bhh[ui + 32];
    float bg = bih[ui + 64] + bhh[ui + 64];
    float bo = bih[ui + 96] + bhh[ui + 96];
#pragma unroll
    for (int r = 0; r < 4; ++r) {
      int n = R0 + r0 + r;
      uint2 qv;
      qv.x = h2bits(__builtin_amdgcn_cvt_pkrtz(acc[p  ][r] + bi, acc[p+4][r] + bg));
      qv.y = h2bits(__builtin_amdgcn_cvt_pkrtz(acc[p+2][r] + bf, acc[p+6][r] + bo));
      G1q[(size_t)n*32 + ui] = qv;
    }
  }
#undef XLOAD
#undef XCVT
#undef MM_REGA
#undef MM_ACT
}

// ---------------------------------------------------------------------------
// LSTM+HEAD fused (v15, R8 verbatim): MFMA scan, 16 rows/wave, head folded
// into each step (2 extra MFMAs -> 27 logits/row; softmax/entropy/logprob
// via cross-lane shfl_xor reductions; pad rows biased to -1e30).
// ---------------------------------------------------------------------------
__global__ __launch_bounds__(64) void lstm_kernel(
    const uint2* __restrict__ G1q, const float* __restrict__ Whh,
    const float* __restrict__ Wh, const float* __restrict__ bh,
    const int* __restrict__ done, const int* __restrict__ actions,
    const float* __restrict__ h0, const float* __restrict__ c0,
    float* __restrict__ out)
{
  static_assert(BA == 512 && NCHUNK == 32, "index math below assumes 512x32");
  const int lane = threadIdx.x;        // 0..63
  const int ln   = lane & 15;          // row within 16-row group / B,C column
  const int q    = lane >> 4;          // quad
  const int rg   = blockIdx.x & 31;    // row group (16 rows)
  const int ck   = blockIdx.x >> 5;    // 0..31 chunk index
  const int R0   = rg * 16;
  const int b    = R0 >> 5;            // batch column (wave-uniform)

  const unsigned long long dm0 = __ballot(done[lane*Bn + b] != 0);        // t 0..63
  const unsigned long long dm1 = __ballot(done[(lane + 64)*Bn + b] != 0); // 64..127

  const int s = (ck == 0) ? 0 : first_done_ge(dm0, dm1, ck * CHUNKW);
  const int e = (ck == NCHUNK - 1) ? Tn
                                   : first_done_ge(dm0, dm1, (ck + 1) * CHUNKW);
  if (s >= e) return;                  // empty chunk

#define WFRAG(DST, ROWBASE, SRC, STRIDE) {                                     \
    const float* p_ = &(SRC)[(size_t)((ROWBASE) + ln)*(STRIDE) + q*8];         \
    float4 c0_ = *(const float4*)p_;                                           \
    float4 c1_ = *(const float4*)(p_ + 4);                                     \
    DST = (half8v){                                                            \
      (_Float16)c0_.x, (_Float16)c0_.y, (_Float16)c0_.z, (_Float16)c0_.w,     \
      (_Float16)c1_.x, (_Float16)c1_.y, (_Float16)c1_.z, (_Float16)c1_.w}; }

  half8v wA0, wA1, wA2, wA3, wA4, wA5, wA6, wA7;
  WFRAG(wA0,   0, Whh, HID)  WFRAG(wA1,  16, Whh, HID)
  WFRAG(wA2,  32, Whh, HID)  WFRAG(wA3,  48, Whh, HID)
  WFRAG(wA4,  64, Whh, HID)  WFRAG(wA5,  80, Whh, HID)
  WFRAG(wA6,  96, Whh, HID)  WFRAG(wA7, 112, Whh, HID)

  half8v whA0, whA1;
  WFRAG(whA0, 0, Wh, HID)
  {
    int row = 16 + ln;
    int rc  = (row < 27) ? row : 0;
    float zf = (row < 27) ? 1.f : 0.f;
    const float* p_ = &Wh[(size_t)rc*HID + q*8];
    float4 c0_ = *(const float4*)p_;
    float4 c1_ = *(const float4*)(p_ + 4);
    whA1 = (half8v){
      (_Float16)(c0_.x*zf), (_Float16)(c0_.y*zf),
      (_Float16)(c0_.z*zf), (_Float16)(c0_.w*zf),
      (_Float16)(c1_.x*zf), (_Float16)(c1_.y*zf),
      (_Float16)(c1_.z*zf), (_Float16)(c1_.w*zf)};
  }
#undef WFRAG

  f32x4 bc0, bc1;
#pragma unroll
  for (int r = 0; r < 4; ++r) {
    int m0 = 4*q + r;
    int m1 = 16 + 4*q + r;
    bc0[r] = bh[m0];
    bc1[r] = (m1 < 27) ? bh[m1] : -1e30f;
  }

#define KOF(M, K, O) int K = (M)/9; K = (K > 2) ? 2 : K; const int O = (M) - 9*K;
  const int mA = 4*q, mB = 16 + 4*q;
  KOF(mA+0, kA0, oA0) KOF(mA+1, kA1, oA1) KOF(mA+2, kA2, oA2) KOF(mA+3, kA3, oA3)
  KOF(mB+0, kB0, oB0) KOF(mB+1, kB1, oB1) KOF(mB+2, kB2, oB2) KOF(mB+3, kB3, oB3)
#undef KOF

  const float4 z4 = {0.f, 0.f, 0.f, 0.f};
  float4 cs0, cs1;
  unsigned w0, w1, w2, w3;
  if (ck == 0) {
    const float* hp = &h0[(size_t)(R0 + ln)*HID + 4*q];
    const float* cp = &c0[(size_t)(R0 + ln)*HID + 4*q];
    float4 ha = *(const float4*)hp;
    float4 hb = *(const float4*)(hp + 16);
    cs0 = *(const float4*)cp;
    cs1 = *(const float4*)(cp + 16);
    w0 = h2bits(__builtin_amdgcn_cvt_pkrtz(ha.x, ha.y));
    w1 = h2bits(__builtin_amdgcn_cvt_pkrtz(ha.z, ha.w));
    w2 = h2bits(__builtin_amdgcn_cvt_pkrtz(hb.x, hb.y));
    w3 = h2bits(__builtin_amdgcn_cvt_pkrtz(hb.z, hb.w));
  } else {
    cs0 = z4; cs1 = z4;
    w0 = w1 = w2 = w3 = 0u;
  }

  const int aA = (ln + ((q & 1) << 5)) << 2;
  const int aB = aA + (16 << 2);
  const bool loq = (q < 2);

#define BBUILD(DST) {                                                      \
    unsigned e0_ = (unsigned)__builtin_amdgcn_ds_bpermute(aA, (int)w0);    \
    unsigned e1_ = (unsigned)__builtin_amdgcn_ds_bpermute(aA, (int)w1);    \
    unsigned e2_ = (unsigned)__builtin_amdgcn_ds_bpermute(aA, (int)w2);    \
    unsigned e3_ = (unsigned)__builtin_amdgcn_ds_bpermute(aA, (int)w3);    \
    unsigned o0_ = (unsigned)__builtin_amdgcn_ds_bpermute(aB, (int)w0);    \
    unsigned o1_ = (unsigned)__builtin_amdgcn_ds_bpermute(aB, (int)w1);    \
    unsigned o2_ = (unsigned)__builtin_amdgcn_ds_bpermute(aB, (int)w2);    \
    unsigned o3_ = (unsigned)__builtin_amdgcn_ds_bpermute(aB, (int)w3);    \
    uint4 bu_;                                                             \
    bu_.x = loq ? e0_ : e2_;  bu_.y = loq ? e1_ : e3_;                     \
    bu_.z = loq ? o0_ : o2_;  bu_.w = loq ? o1_ : o3_;                     \
    DST = __builtin_bit_cast(half8v, bu_); }

  half8v Bprev;
  if (ck == 0) { BBUILD(Bprev) }
  else {
    uint4 zz; zz.x = zz.y = zz.z = zz.w = 0u;
    Bprev = __builtin_bit_cast(half8v, zz);
  }

  const uint2* gb = G1q + ((size_t)(R0 + ln) * 32 + 4*q);
  const size_t gstep = (size_t)BA * 32;          // uint2 per t

#define LOADG(T, A0, A1, A2, A3)                                  \
  { const uint2* p_ = gb + (size_t)(T) * gstep;                   \
    A0 = *(const uint4*)(p_);      A1 = *(const uint4*)(p_ + 2);  \
    A2 = *(const uint4*)(p_ + 16); A3 = *(const uint4*)(p_ + 18); }

  uint4 rc0, rc1, rc2, rc3;
  LOADG(s, rc0, rc1, rc2, rc3);

  for (int t = s; t < e; ++t) {
    int tn = (t + 1 < e) ? t + 1 : e - 1;
    uint4 rn0, rn1, rn2, rn3;
    LOADG(tn, rn0, rn1, rn2, rn3);             // prefetch next step

    const int rowG = t*BA + R0 + ln;
    const int* ap = actions + (size_t)rowG*3;
    int a0 = ap[0], a1 = ap[1], a2 = ap[2];

    unsigned long long dbit = (t < 64) ? (dm0 >> t) : (dm1 >> (t - 64));
    half8v Buse = Bprev;
    if (dbit & 1ull) {                         // reset: h=0 (B=0), c=0
      uint4 zz; zz.x = zz.y = zz.z = zz.w = 0u;
      Buse = __builtin_bit_cast(half8v, zz);
      cs0 = z4; cs1 = z4;
    }

    f32x4 ci0, cf0, cg0, co0, ci1, cf1, cg1, co1;
    {
      pk16x2 ig, fo;
      ig = bits2h(rc0.x); fo = bits2h(rc0.y);
      ci0[0] = ig.x; cg0[0] = ig.y; cf0[0] = fo.x; co0[0] = fo.y;
      ig = bits2h(rc0.z); fo = bits2h(rc0.w);
      ci0[1] = ig.x; cg0[1] = ig.y; cf0[1] = fo.x; co0[1] = fo.y;
      ig = bits2h(rc1.x); fo = bits2h(rc1.y);
      ci0[2] = ig.x; cg0[2] = ig.y; cf0[2] = fo.x; co0[2] = fo.y;
      ig = bits2h(rc1.z); fo = bits2h(rc1.w);
      ci0[3] = ig.x; cg0[3] = ig.y; cf0[3] = fo.x; co0[3] = fo.y;
      ig = bits2h(rc2.x); fo = bits2h(rc2.y);
      ci1[0] = ig.x; cg1[0] = ig.y; cf1[0] = fo.x; co1[0] = fo.y;
      ig = bits2h(rc2.z); fo = bits2h(rc2.w);
      ci1[1] = ig.x; cg1[1] = ig.y; cf1[1] = fo.x; co1[1] = fo.y;
      ig = bits2h(rc3.x); fo = bits2h(rc3.y);
      ci1[2] = ig.x; cg1[2] = ig.y; cf1[2] = fo.x; co1[2] = fo.y;
      ig = bits2h(rc3.z); fo = bits2h(rc3.w);
      ci1[3] = ig.x; cg1[3] = ig.y; cf1[3] = fo.x; co1[3] = fo.y;
    }

    f32x4 ai0 = __builtin_amdgcn_mfma_f32_16x16x32_f16(wA0, Buse, ci0, 0, 0, 0);
    f32x4 ai1 = __builtin_amdgcn_mfma_f32_16x16x32_f16(wA1, Buse, ci1, 0, 0, 0);
    f32x4 af0 = __builtin_amdgcn_mfma_f32_16x16x32_f16(wA2, Buse, cf0, 0, 0, 0);
    f32x4 af1 = __builtin_amdgcn_mfma_f32_16x16x32_f16(wA3, Buse, cf1, 0, 0, 0);
    f32x4 ag0 = __builtin_amdgcn_mfma_f32_16x16x32_f16(wA4, Buse, cg0, 0, 0, 0);
    f32x4 ag1 = __builtin_amdgcn_mfma_f32_16x16x32_f16(wA5, Buse, cg1, 0, 0, 0);
    f32x4 ao0 = __builtin_amdgcn_mfma_f32_16x16x32_f16(wA6, Buse, co0, 0, 0, 0);
    f32x4 ao1 = __builtin_amdgcn_mfma_f32_16x16x32_f16(wA7, Buse, co1, 0, 0, 0);

    f32x4 hva, hvb;
#pragma unroll
    for (int r = 0; r < 4; ++r) {
      float iv = fast_sig(ai0[r]);
      float fv = fast_sig(af0[r]);
      float gv = fast_tanh(ag0[r]);
      float ov = fast_sig(ao0[r]);
      float cc = fmaf(fv, cs0[r], iv * gv);
      cs0[r] = cc;
      hva[r] = ov * fast_tanh(cc);
    }
#pragma unroll
    for (int r = 0; r < 4; ++r) {
      float iv = fast_sig(ai1[r]);
      float fv = fast_sig(af1[r]);
      float gv = fast_tanh(ag1[r]);
      float ov = fast_sig(ao1[r]);
      float cc = fmaf(fv, cs1[r], iv * gv);
      cs1[r] = cc;
      hvb[r] = ov * fast_tanh(cc);
    }

    w0 = h2bits(__builtin_amdgcn_cvt_pkrtz(hva[0], hva[1]));
    w1 = h2bits(__builtin_amdgcn_cvt_pkrtz(hva[2], hva[3]));
    w2 = h2bits(__builtin_amdgcn_cvt_pkrtz(hvb[0], hvb[1]));
    w3 = h2bits(__builtin_amdgcn_cvt_pkrtz(hvb[2], hvb[3]));
    BBUILD(Bprev)

    // ---- fused head ----
    f32x4 lh0 = __builtin_amdgcn_mfma_f32_16x16x32_f16(whA0, Bprev, bc0, 0, 0, 0);
    f32x4 lh1 = __builtin_amdgcn_mfma_f32_16x16x32_f16(whA1, Bprev, bc1, 0, 0, 0);

    float mx0 = -1e30f, mx1 = -1e30f, mx2 = -1e30f;
    bmax3(mx0, mx1, mx2, kA0, lh0[0]); bmax3(mx0, mx1, mx2, kA1, lh0[1]);
    bmax3(mx0, mx1, mx2, kA2, lh0[2]); bmax3(mx0, mx1, mx2, kA3, lh0[3]);
    bmax3(mx0, mx1, mx2, kB0, lh1[0]); bmax3(mx0, mx1, mx2, kB1, lh1[1]);
    bmax3(mx0, mx1, mx2, kB2, lh1[2]); bmax3(mx0, mx1, mx2, kB3, lh1[3]);
    mx0 = fmaxf(mx0, __shfl_xor(mx0, 16)); mx0 = fmaxf(mx0, __shfl_xor(mx0, 32));
    mx1 = fmaxf(mx1, __shfl_xor(mx1, 16)); mx1 = fmaxf(mx1, __shfl_xor(mx1, 32));
    mx2 = fmaxf(mx2, __shfl_xor(mx2, 16)); mx2 = fmaxf(mx2, __shfl_xor(mx2, 32));

    float ev0 = __expf(lh0[0] - bsel3(mx0, mx1, mx2, kA0));
    float ev1 = __expf(lh0[1] - bsel3(mx0, mx1, mx2, kA1));
    float ev2 = __expf(lh0[2] - bsel3(mx0, mx1, mx2, kA2));
    float ev3 = __expf(lh0[3] - bsel3(mx0, mx1, mx2, kA3));
    float ev4 = __expf(lh1[0] - bsel3(mx0, mx1, mx2, kB0));
    float ev5 = __expf(lh1[1] - bsel3(mx0, mx1, mx2, kB1));
    float ev6 = __expf(lh1[2] - bsel3(mx0, mx1, mx2, kB2));
    float ev7 = __expf(lh1[3] - bsel3(mx0, mx1, mx2, kB3));
    float s0 = 0.f, s1 = 0.f, s2 = 0.f;
    badd3(s0, s1, s2, kA0, ev0); badd3(s0, s1, s2, kA1, ev1);
    badd3(s0, s1, s2, kA2, ev2); badd3(s0, s1, s2, kA3, ev3);
    badd3(s0, s1, s2, kB0, ev4); badd3(s0, s1, s2, kB1, ev5);
    badd3(s0, s1, s2, kB2, ev6); badd3(s0, s1, s2, kB3, ev7);
    s0 += __shfl_xor(s0, 16); s0 += __shfl_xor(s0, 32);
    s1 += __shfl_xor(s1, 16); s1 += __shfl_xor(s1, 32);
    s2 += __shfl_xor(s2, 16); s2 += __shfl_xor(s2, 32);
    float lse0 = mx0 + __logf(s0);
    float lse1 = mx1 + __logf(s1);
    float lse2 = mx2 + __logf(s2);
    float sc0 = __expf(mx0 - lse0);
    float sc1 = __expf(mx1 - lse1);
    float sc2 = __expf(mx2 - lse2);

    float en0 = 0.f, en1 = 0.f, en2 = 0.f;
    float pl = 1.f;
#define HSLOT(LV, EV, KM, OM) {                                \
      float lse_ = bsel3(lse0, lse1, lse2, KM);                \
      float lp_  = (LV) - lse_;                                \
      float p_   = (EV) * bsel3(sc0, sc1, sc2, KM);            \
      badd3(en0, en1, en2, KM, -p_ * lp_);                     \
      int a_ = bseli3(a0, a1, a2, KM);                         \
      pl = ((OM) == a_) ? pl * lp_ : pl; }
    HSLOT(lh0[0], ev0, kA0, oA0) HSLOT(lh0[1], ev1, kA1, oA1)
    HSLOT(lh0[2], ev2, kA2, oA2) HSLOT(lh0[3], ev3, kA3, oA3)
    HSLOT(lh1[0], ev4, kB0, oB0) HSLOT(lh1[1], ev5, kB1, oB1)
    HSLOT(lh1[2], ev6, kB2, oB2) HSLOT(lh1[3], ev7, kB3, oB3)
#undef HSLOT
    en0 += __shfl_xor(en0, 16); en0 += __shfl_xor(en0, 32);
    en1 += __shfl_xor(en1, 16); en1 += __shfl_xor(en1, 32);
    en2 += __shfl_xor(en2, 16); en2 += __shfl_xor(en2, 32);
    pl  *= __shfl_xor(pl, 16);  pl  *= __shfl_xor(pl, 32);

    if (q == 0) {
      float* ob = out + (size_t)rowG*3;
      ob[0] = (float)a0; ob[1] = (float)a1; ob[2] = (float)a2;   // actions echo
      float* eb = out + OUT_ENT + (size_t)rowG*3;
      eb[0] = en0; eb[1] = en1; eb[2] = en2;                      // entropies
      out[OUT_LP + rowG] = pl;                                    // logprob
    }

    rc0 = rn0; rc1 = rn1; rc2 = rn2; rc3 = rn3;
  }
#undef LOADG
#undef BBUILD
}

extern "C" void kernel_launch(void* const* d_in, const int* in_sizes, int n_in,
                              void* d_out, int out_size, void* d_ws, size_t ws_size,
                              hipStream_t stream)
{
  const float* x       = (const float*)d_in[0];
  const int*   done    = (const int*)  d_in[1];
  const int*   actions = (const int*)  d_in[2];
  const float* W1  = (const float*)d_in[3];
  const float* b1  = (const float*)d_in[4];
  const float* W2  = (const float*)d_in[5];
  const float* b2  = (const float*)d_in[6];
  const float* W3  = (const float*)d_in[7];
  const float* b3  = (const float*)d_in[8];
  const float* Wih = (const float*)d_in[9];
  const float* Whh = (const float*)d_in[10];
  const float* bih = (const float*)d_in[11];
  const float* bhh = (const float*)d_in[12];
  const float* Wh  = (const float*)d_in[13];
  const float* bh  = (const float*)d_in[14];
  const float* h0  = (const float*)d_in[15];
  const float* c0  = (const float*)d_in[16];
  float* out = (float*)d_out;

  uint2* G1q = (uint2*)d_ws;                   // TBA*32 uint2 = 16.8 MB

  mlp_kernel<<<TBA/128, 512, 0, stream>>>(
      x, W1, W2, W3, Wih, b1, b2, b3, bih, bhh, G1q);
  lstm_kernel<<<32 * NCHUNK, 64, 0, stream>>>(
      G1q, Whh, Wh, bh, done, actions, h0, c0, out);
}

// Round 13
// 167.770 us; speedup vs baseline: 1.5742x; 1.5742x over previous
//
#include <hip/hip_runtime.h>
#include <math.h>

namespace {
constexpr int Tn = 128, Bn = 16, An = 32, OBS = 256, Kh = 3, NACT = 9, HID = 32;
constexpr int TBA = Tn * Bn * An;   // 65536 rows through the MLP
constexpr int BA  = Bn * An;        // 512 LSTM sequences
constexpr int OUT_LP  = TBA * Kh;         // 196608: logprobs start
constexpr int OUT_ENT = TBA * Kh + TBA;   // 262144: entropies start
constexpr int NCHUNK = 32;                // time-chunks per row (done-reset cuts)
constexpr int CHUNKW = Tn / NCHUNK;       // nominal chunk width (4)

typedef __fp16   pk16x2 __attribute__((ext_vector_type(2)));  // builtin-compatible
typedef _Float16 half8v __attribute__((ext_vector_type(8)));
typedef float    f32x4  __attribute__((ext_vector_type(4)));
}

__device__ __forceinline__ float fast_sig(float x) {
  return __builtin_amdgcn_rcpf(1.f + __expf(-x));
}
__device__ __forceinline__ float fast_tanh(float x) {   // 2*sig(2x)-1, saturates safely
  return fmaf(2.f, fast_sig(2.f * x), -1.f);
}
__device__ __forceinline__ unsigned h2bits(pk16x2 h) {
  return __builtin_bit_cast(unsigned, h);
}
__device__ __forceinline__ pk16x2 bits2h(unsigned u) {
  return __builtin_bit_cast(pk16x2, u);
}
// first set bit index >= n in the 128-bit mask {dm0, dm1}; 128 if none.
__device__ __forceinline__ int first_done_ge(unsigned long long dm0,
                                             unsigned long long dm1, int n) {
  unsigned long long m0 = (n < 64) ? (dm0 & (~0ull << n)) : 0ull;
  unsigned long long m1 = (n < 64) ? dm1 : (dm1 & (~0ull << (n - 64)));
  if (m0) return __builtin_ctzll(m0);
  if (m1) return 64 + __builtin_ctzll(m1);
  return 128;
}
// 3-bucket helpers (runtime bucket index km, no arrays -> no scratch)
__device__ __forceinline__ void bmax3(float& m0, float& m1, float& m2,
                                      int km, float v) {
  m0 = (km == 0) ? fmaxf(m0, v) : m0;
  m1 = (km == 1) ? fmaxf(m1, v) : m1;
  m2 = (km == 2) ? fmaxf(m2, v) : m2;
}
__device__ __forceinline__ void badd3(float& s0, float& s1, float& s2,
                                      int km, float v) {
  s0 += (km == 0) ? v : 0.f;
  s1 += (km == 1) ? v : 0.f;
  s2 += (km == 2) ? v : 0.f;
}
__device__ __forceinline__ float bsel3(float x0, float x1, float x2, int km) {
  return (km == 0) ? x0 : ((km == 1) ? x1 : x2);
}
__device__ __forceinline__ int bseli3(int x0, int x1, int x2, int km) {
  return (km == 0) ? x0 : ((km == 1) ? x1 : x2);
}

// ---------------------------------------------------------------------------
// MLP v5 (best measured): inline fp32->fp16 weight conversion in LDS stage,
// barrier-minimized register-A pipeline, wt double-buffered, act wave-private.
// ---------------------------------------------------------------------------
template<int ROWS, int WSTR>
__device__ __forceinline__ void stage_whf(const float* __restrict__ Wg, int kofs,
                                          _Float16* __restrict__ wt, int tid)
{
#pragma unroll
  for (int it = 0; it < ROWS/64; ++it) {        // ROWS*8 units / 512 threads
    int idx = tid + it*512;
    int o = idx >> 3, g8 = idx & 7;
    const float* p = &Wg[(size_t)o*WSTR + kofs + g8*8];
    float4 c0 = *(const float4*)p;
    float4 c1 = *(const float4*)(p + 4);
    half8v hv = { (_Float16)c0.x, (_Float16)c0.y, (_Float16)c0.z, (_Float16)c0.w,
                  (_Float16)c1.x, (_Float16)c1.y, (_Float16)c1.z, (_Float16)c1.w };
    *(half8v*)&wt[o*72 + g8*8] = hv;
  }
}

template<int NOC, int XSTR>
__device__ __forceinline__ void mfma_slab(const _Float16* __restrict__ xsrc,
                                          const _Float16* __restrict__ wt,
                                          int rA, int ln, int quad, f32x4 acc[8])
{
#pragma unroll
  for (int kc = 0; kc < 2; ++kc) {
    half8v a = *(const half8v*)&xsrc[rA*XSTR + kc*32 + quad*8];
#pragma unroll
    for (int oc = 0; oc < NOC; ++oc) {
      half8v b = *(const half8v*)&wt[(oc*16 + ln)*72 + kc*32 + quad*8];
      acc[oc] = __builtin_amdgcn_mfma_f32_16x16x32_f16(a, b, acc[oc], 0, 0, 0);
    }
  }
}

template<int NOC>
__device__ __forceinline__ void mfma_regA(half8v a0, half8v a1,
                                          const _Float16* __restrict__ wt,
                                          int ln, int quad, f32x4 acc[8])
{
#pragma unroll
  for (int oc = 0; oc < NOC; ++oc) {
    half8v b = *(const half8v*)&wt[(oc*16 + ln)*72 + quad*8];
    acc[oc] = __builtin_amdgcn_mfma_f32_16x16x32_f16(a0, b, acc[oc], 0, 0, 0);
  }
#pragma unroll
  for (int oc = 0; oc < NOC; ++oc) {
    half8v b = *(const half8v*)&wt[(oc*16 + ln)*72 + 32 + quad*8];
    acc[oc] = __builtin_amdgcn_mfma_f32_16x16x32_f16(a1, b, acc[oc], 0, 0, 0);
  }
}

__global__ __launch_bounds__(512, 4) void mlp_kernel(
    const float* __restrict__ x,
    const float* __restrict__ W1, const float* __restrict__ W2,
    const float* __restrict__ W3, const float* __restrict__ Wih,
    const float* __restrict__ b1, const float* __restrict__ b2,
    const float* __restrict__ b3, const float* __restrict__ bih,
    const float* __restrict__ bhh, uint2* __restrict__ G1q)
{
  __shared__ __align__(16) _Float16 wt0[128*72];   // weight slab ping
  __shared__ __align__(16) _Float16 wt1[128*72];   // weight slab pong
  __shared__ __align__(16) _Float16 act[128*136];  // activations (wave-private rows)
  const int tid  = threadIdx.x;                // 0..511
  const int w    = tid >> 6;                   // 0..7
  const int lane = tid & 63;
  const int ln   = lane & 15;
  const int quad = lane >> 4;
  const int rA   = 16*w + ln;                  // 0..127
  const int r0   = 16*w + quad*4;
  const int R0   = blockIdx.x * 128;
  f32x4 acc[8];
  const float* xrow = &x[(size_t)(R0 + rA)*OBS + quad*8];

#define XLOAD(KT, U0, U1, U2, U3) {                                   \
    const float* xp_ = xrow + (KT)*64;                                \
    U0 = *(const float4*)(xp_);      U1 = *(const float4*)(xp_ + 4);  \
    U2 = *(const float4*)(xp_ + 32); U3 = *(const float4*)(xp_ + 36); }
#define XCVT(U0, U1, U2, U3, A0, A1) {                                         \
    A0 = (half8v){(_Float16)U0.x,(_Float16)U0.y,(_Float16)U0.z,(_Float16)U0.w, \
                  (_Float16)U1.x,(_Float16)U1.y,(_Float16)U1.z,(_Float16)U1.w};\
    A1 = (half8v){(_Float16)U2.x,(_Float16)U2.y,(_Float16)U2.z,(_Float16)U2.w, \
                  (_Float16)U3.x,(_Float16)U3.y,(_Float16)U3.z,(_Float16)U3.w}; }

  float4 u0, u1, u2, u3, v0, v1, v2, v3;
  half8v a0, a1;

  // prologue: x frags for kt0 + W1 slab0
  XLOAD(0, u0, u1, u2, u3);
  stage_whf<128, 256>(W1, 0, wt0, tid);
#pragma unroll
  for (int oc = 0; oc < 8; ++oc) acc[oc] = (f32x4)0.f;
  __syncthreads();

  // ---- layer 1: 256 -> 128 (4 phases, one barrier each) ----
  stage_whf<128, 256>(W1, 64, wt1, tid);       // p0: stage s1, compute s0
  XLOAD(1, v0, v1, v2, v3);
  XCVT(u0, u1, u2, u3, a0, a1);
  mfma_regA<8>(a0, a1, wt0, ln, quad, acc);
  __syncthreads();

  stage_whf<128, 256>(W1, 128, wt0, tid);      // p1
  XLOAD(2, u0, u1, u2, u3);
  XCVT(v0, v1, v2, v3, a0, a1);
  mfma_regA<8>(a0, a1, wt1, ln, quad, acc);
  __syncthreads();

  stage_whf<128, 256>(W1, 192, wt1, tid);      // p2
  XLOAD(3, v0, v1, v2, v3);
  XCVT(u0, u1, u2, u3, a0, a1);
  mfma_regA<8>(a0, a1, wt0, ln, quad, acc);
  __syncthreads();

  stage_whf<128, 128>(W2, 0, wt0, tid);        // p3: stage W2 s0
  XCVT(v0, v1, v2, v3, a0, a1);
  mfma_regA<8>(a0, a1, wt1, ln, quad, acc);
  __syncthreads();

  // L1 epilogue (wave-private act rows; no barrier needed)
#pragma unroll
  for (int oc = 0; oc < 8; ++oc) {
    int o = oc*16 + ln;
    float bv = b1[o];
#pragma unroll
    for (int r = 0; r < 4; ++r)
      act[(r0 + r)*136 + o] = (_Float16)fast_tanh(acc[oc][r] + bv);
  }

  // ---- layer 2: 128 -> 128 (2 phases) ----
#pragma unroll
  for (int oc = 0; oc < 8; ++oc) acc[oc] = (f32x4)0.f;
  stage_whf<128, 128>(W2, 64, wt1, tid);       // p4
  mfma_slab<8, 136>(act, wt0, rA, ln, quad, acc);
  __syncthreads();

  stage_whf<64, 128>(W3, 0, wt0, tid);         // p5: stage W3 s0
  mfma_slab<8, 136>(act + 64, wt1, rA, ln, quad, acc);
  __syncthreads();

#pragma unroll
  for (int oc = 0; oc < 8; ++oc) {
    int o = oc*16 + ln;
    float bv = b2[o];
#pragma unroll
    for (int r = 0; r < 4; ++r)
      act[(r0 + r)*136 + o] = (_Float16)fast_tanh(acc[oc][r] + bv);
  }

  // ---- layer 3: 128 -> 64 (2 phases) ----
#pragma unroll
  for (int oc = 0; oc < 4; ++oc) acc[oc] = (f32x4)0.f;
  stage_whf<64, 128>(W3, 64, wt1, tid);        // p6
  mfma_slab<4, 136>(act, wt0, rA, ln, quad, acc);
  __syncthreads();

  stage_whf<128, 64>(Wih, 0, wt0, tid);        // p7: stage Wih
  mfma_slab<4, 136>(act + 64, wt1, rA, ln, quad, acc);
  __syncthreads();

  // L3 epilogue: z -> act cols 0..63 (wave-private)
#pragma unroll
  for (int oc = 0; oc < 4; ++oc) {
    int o = oc*16 + ln;
    float bv = b3[o];
#pragma unroll
    for (int r = 0; r < 4; ++r)
      act[(r0 + r)*136 + o] = (_Float16)(acc[oc][r] + bv);
  }

  // ---- layer 4: z(64) -> 128 gate inputs (p8, no trailing barrier) ----
#pragma unroll
  for (int oc = 0; oc < 8; ++oc) acc[oc] = (f32x4)0.f;
  mfma_slab<8, 136>(act, wt0, rA, ln, quad, acc);
#pragma unroll
  for (int p = 0; p < 2; ++p) {
    int ui = p*16 + ln;
    float bi = bih[ui]      + bhh[ui];
    float bf = bih[ui + 32] + bhh[ui + 32];
    float bg = bih[ui + 64] + bhh[ui + 64];
    float bo = bih[ui + 96] + bhh[ui + 96];
#pragma unroll
    for (int r = 0; r < 4; ++r) {
      int n = R0 + r0 + r;
      uint2 qv;
      qv.x = h2bits(__builtin_amdgcn_cvt_pkrtz(acc[p  ][r] + bi, acc[p+4][r] + bg));
      qv.y = h2bits(__builtin_amdgcn_cvt_pkrtz(acc[p+2][r] + bf, acc[p+6][r] + bo));
      G1q[(size_t)n*32 + ui] = qv;
    }
  }
#undef XLOAD
#undef XCVT
}

// ---------------------------------------------------------------------------
// LSTM+HEAD fused (v15): MFMA scan, 16 rows/wave, head folded into each step
// (2 extra MFMAs -> 27 logits/row; softmax/entropy/logprob via cross-lane
// shfl_xor reductions; pad rows biased to -1e30).
// ---------------------------------------------------------------------------
__global__ __launch_bounds__(64) void lstm_kernel(
    const uint2* __restrict__ G1q, const float* __restrict__ Whh,
    const float* __restrict__ Wh, const float* __restrict__ bh,
    const int* __restrict__ done, const int* __restrict__ actions,
    const float* __restrict__ h0, const float* __restrict__ c0,
    float* __restrict__ out)
{
  static_assert(BA == 512 && NCHUNK == 32, "index math below assumes 512x32");
  const int lane = threadIdx.x;        // 0..63
  const int ln   = lane & 15;          // row within 16-row group / B,C column
  const int q    = lane >> 4;          // quad
  const int rg   = blockIdx.x & 31;    // row group (16 rows)
  const int ck   = blockIdx.x >> 5;    // 0..31 chunk index
  const int R0   = rg * 16;
  const int b    = R0 >> 5;            // batch column (wave-uniform)

  const unsigned long long dm0 = __ballot(done[lane*Bn + b] != 0);        // t 0..63
  const unsigned long long dm1 = __ballot(done[(lane + 64)*Bn + b] != 0); // 64..127

  const int s = (ck == 0) ? 0 : first_done_ge(dm0, dm1, ck * CHUNKW);
  const int e = (ck == NCHUNK - 1) ? Tn
                                   : first_done_ge(dm0, dm1, (ck + 1) * CHUNKW);
  if (s >= e) return;                  // empty chunk

#define WFRAG(DST, ROWBASE, SRC, STRIDE) {                                     \
    const float* p_ = &(SRC)[(size_t)((ROWBASE) + ln)*(STRIDE) + q*8];         \
    float4 c0_ = *(const float4*)p_;                                           \
    float4 c1_ = *(const float4*)(p_ + 4);                                     \
    DST = (half8v){                                                            \
      (_Float16)c0_.x, (_Float16)c0_.y, (_Float16)c0_.z, (_Float16)c0_.w,     \
      (_Float16)c1_.x, (_Float16)c1_.y, (_Float16)c1_.z, (_Float16)c1_.w}; }

  half8v wA0, wA1, wA2, wA3, wA4, wA5, wA6, wA7;
  WFRAG(wA0,   0, Whh, HID)  WFRAG(wA1,  16, Whh, HID)
  WFRAG(wA2,  32, Whh, HID)  WFRAG(wA3,  48, Whh, HID)
  WFRAG(wA4,  64, Whh, HID)  WFRAG(wA5,  80, Whh, HID)
  WFRAG(wA6,  96, Whh, HID)  WFRAG(wA7, 112, Whh, HID)

  half8v whA0, whA1;
  WFRAG(whA0, 0, Wh, HID)
  {
    int row = 16 + ln;
    int rc  = (row < 27) ? row : 0;
    float zf = (row < 27) ? 1.f : 0.f;
    const float* p_ = &Wh[(size_t)rc*HID + q*8];
    float4 c0_ = *(const float4*)p_;
    float4 c1_ = *(const float4*)(p_ + 4);
    whA1 = (half8v){
      (_Float16)(c0_.x*zf), (_Float16)(c0_.y*zf),
      (_Float16)(c0_.z*zf), (_Float16)(c0_.w*zf),
      (_Float16)(c1_.x*zf), (_Float16)(c1_.y*zf),
      (_Float16)(c1_.z*zf), (_Float16)(c1_.w*zf)};
  }
#undef WFRAG

  f32x4 bc0, bc1;
#pragma unroll
  for (int r = 0; r < 4; ++r) {
    int m0 = 4*q + r;
    int m1 = 16 + 4*q + r;
    bc0[r] = bh[m0];
    bc1[r] = (m1 < 27) ? bh[m1] : -1e30f;
  }

#define KOF(M, K, O) int K = (M)/9; K = (K > 2) ? 2 : K; const int O = (M) - 9*K;
  const int mA = 4*q, mB = 16 + 4*q;
  KOF(mA+0, kA0, oA0) KOF(mA+1, kA1, oA1) KOF(mA+2, kA2, oA2) KOF(mA+3, kA3, oA3)
  KOF(mB+0, kB0, oB0) KOF(mB+1, kB1, oB1) KOF(mB+2, kB2, oB2) KOF(mB+3, kB3, oB3)
#undef KOF

  const float4 z4 = {0.f, 0.f, 0.f, 0.f};
  float4 cs0, cs1;
  unsigned w0, w1, w2, w3;
  if (ck == 0) {
    const float* hp = &h0[(size_t)(R0 + ln)*HID + 4*q];
    const float* cp = &c0[(size_t)(R0 + ln)*HID + 4*q];
    float4 ha = *(const float4*)hp;
    float4 hb = *(const float4*)(hp + 16);
    cs0 = *(const float4*)cp;
    cs1 = *(const float4*)(cp + 16);
    w0 = h2bits(__builtin_amdgcn_cvt_pkrtz(ha.x, ha.y));
    w1 = h2bits(__builtin_amdgcn_cvt_pkrtz(ha.z, ha.w));
    w2 = h2bits(__builtin_amdgcn_cvt_pkrtz(hb.x, hb.y));
    w3 = h2bits(__builtin_amdgcn_cvt_pkrtz(hb.z, hb.w));
  } else {
    cs0 = z4; cs1 = z4;
    w0 = w1 = w2 = w3 = 0u;
  }

  const int aA = (ln + ((q & 1) << 5)) << 2;
  const int aB = aA + (16 << 2);
  const bool loq = (q < 2);

#define BBUILD(DST) {                                                      \
    unsigned e0_ = (unsigned)__builtin_amdgcn_ds_bpermute(aA, (int)w0);    \
    unsigned e1_ = (unsigned)__builtin_amdgcn_ds_bpermute(aA, (int)w1);    \
    unsigned e2_ = (unsigned)__builtin_amdgcn_ds_bpermute(aA, (int)w2);    \
    unsigned e3_ = (unsigned)__builtin_amdgcn_ds_bpermute(aA, (int)w3);    \
    unsigned o0_ = (unsigned)__builtin_amdgcn_ds_bpermute(aB, (int)w0);    \
    unsigned o1_ = (unsigned)__builtin_amdgcn_ds_bpermute(aB, (int)w1);    \
    unsigned o2_ = (unsigned)__builtin_amdgcn_ds_bpermute(aB, (int)w2);    \
    unsigned o3_ = (unsigned)__builtin_amdgcn_ds_bpermute(aB, (int)w3);    \
    uint4 bu_;                                                             \
    bu_.x = loq ? e0_ : e2_;  bu_.y = loq ? e1_ : e3_;                     \
    bu_.z = loq ? o0_ : o2_;  bu_.w = loq ? o1_ : o3_;                     \
    DST = __builtin_bit_cast(half8v, bu_); }

  half8v Bprev;
  if (ck == 0) { BBUILD(Bprev) }
  else {
    uint4 zz; zz.x = zz.y = zz.z = zz.w = 0u;
    Bprev = __builtin_bit_cast(half8v, zz);
  }

  const uint2* gb = G1q + ((size_t)(R0 + ln) * 32 + 4*q);
  const size_t gstep = (size_t)BA * 32;          // uint2 per t

#define LOADG(T, A0, A1, A2, A3)                                  \
  { const uint2* p_ = gb + (size_t)(T) * gstep;                   \
    A0 = *(const uint4*)(p_);      A1 = *(const uint4*)(p_ + 2);  \
    A2 = *(const uint4*)(p_ + 16); A3 = *(const uint4*)(p_ + 18); }

  uint4 rc0, rc1, rc2, rc3;
  LOADG(s, rc0, rc1, rc2, rc3);

  for (int t = s; t < e; ++t) {
    int tn = (t + 1 < e) ? t + 1 : e - 1;
    uint4 rn0, rn1, rn2, rn3;
    LOADG(tn, rn0, rn1, rn2, rn3);             // prefetch next step

    const int rowG = t*BA + R0 + ln;
    const int* ap = actions + (size_t)rowG*3;
    int a0 = ap[0], a1 = ap[1], a2 = ap[2];

    unsigned long long dbit = (t < 64) ? (dm0 >> t) : (dm1 >> (t - 64));
    half8v Buse = Bprev;
    if (dbit & 1ull) {                         // reset: h=0 (B=0), c=0
      uint4 zz; zz.x = zz.y = zz.z = zz.w = 0u;
      Buse = __builtin_bit_cast(half8v, zz);
      cs0 = z4; cs1 = z4;
    }

    f32x4 ci0, cf0, cg0, co0, ci1, cf1, cg1, co1;
    {
      pk16x2 ig, fo;
      ig = bits2h(rc0.x); fo = bits2h(rc0.y);
      ci0[0] = ig.x; cg0[0] = ig.y; cf0[0] = fo.x; co0[0] = fo.y;
      ig = bits2h(rc0.z); fo = bits2h(rc0.w);
      ci0[1] = ig.x; cg0[1] = ig.y; cf0[1] = fo.x; co0[1] = fo.y;
      ig = bits2h(rc1.x); fo = bits2h(rc1.y);
      ci0[2] = ig.x; cg0[2] = ig.y; cf0[2] = fo.x; co0[2] = fo.y;
      ig = bits2h(rc1.z); fo = bits2h(rc1.w);
      ci0[3] = ig.x; cg0[3] = ig.y; cf0[3] = fo.x; co0[3] = fo.y;
      ig = bits2h(rc2.x); fo = bits2h(rc2.y);
      ci1[0] = ig.x; cg1[0] = ig.y; cf1[0] = fo.x; co1[0] = fo.y;
      ig = bits2h(rc2.z); fo = bits2h(rc2.w);
      ci1[1] = ig.x; cg1[1] = ig.y; cf1[1] = fo.x; co1[1] = fo.y;
      ig = bits2h(rc3.x); fo = bits2h(rc3.y);
      ci1[2] = ig.x; cg1[2] = ig.y; cf1[2] = fo.x; co1[2] = fo.y;
      ig = bits2h(rc3.z); fo = bits2h(rc3.w);
      ci1[3] = ig.x; cg1[3] = ig.y; cf1[3] = fo.x; co1[3] = fo.y;
    }

    f32x4 ai0 = __builtin_amdgcn_mfma_f32_16x16x32_f16(wA0, Buse, ci0, 0, 0, 0);
    f32x4 ai1 = __builtin_amdgcn_mfma_f32_16x16x32_f16(wA1, Buse, ci1, 0, 0, 0);
    f32x4 af0 = __builtin_amdgcn_mfma_f32_16x16x32_f16(wA2, Buse, cf0, 0, 0, 0);
    f32x4 af1 = __builtin_amdgcn_mfma_f32_16x16x32_f16(wA3, Buse, cf1, 0, 0, 0);
    f32x4 ag0 = __builtin_amdgcn_mfma_f32_16x16x32_f16(wA4, Buse, cg0, 0, 0, 0);
    f32x4 ag1 = __builtin_amdgcn_mfma_f32_16x16x32_f16(wA5, Buse, cg1, 0, 0, 0);
    f32x4 ao0 = __builtin_amdgcn_mfma_f32_16x16x32_f16(wA6, Buse, co0, 0, 0, 0);
    f32x4 ao1 = __builtin_amdgcn_mfma_f32_16x16x32_f16(wA7, Buse, co1, 0, 0, 0);

    f32x4 hva, hvb;
#pragma unroll
    for (int r = 0; r < 4; ++r) {
      float iv = fast_sig(ai0[r]);
      float fv = fast_sig(af0[r]);
      float gv = fast_tanh(ag0[r]);
      float ov = fast_sig(ao0[r]);
      float cc = fmaf(fv, cs0[r], iv * gv);
      cs0[r] = cc;
      hva[r] = ov * fast_tanh(cc);
    }
#pragma unroll
    for (int r = 0; r < 4; ++r) {
      float iv = fast_sig(ai1[r]);
      float fv = fast_sig(af1[r]);
      float gv = fast_tanh(ag1[r]);
      float ov = fast_sig(ao1[r]);
      float cc = fmaf(fv, cs1[r], iv * gv);
      cs1[r] = cc;
      hvb[r] = ov * fast_tanh(cc);
    }

    w0 = h2bits(__builtin_amdgcn_cvt_pkrtz(hva[0], hva[1]));
    w1 = h2bits(__builtin_amdgcn_cvt_pkrtz(hva[2], hva[3]));
    w2 = h2bits(__builtin_amdgcn_cvt_pkrtz(hvb[0], hvb[1]));
    w3 = h2bits(__builtin_amdgcn_cvt_pkrtz(hvb[2], hvb[3]));
    BBUILD(Bprev)

    // ---- fused head ----
    f32x4 lh0 = __builtin_amdgcn_mfma_f32_16x16x32_f16(whA0, Bprev, bc0, 0, 0, 0);
    f32x4 lh1 = __builtin_amdgcn_mfma_f32_16x16x32_f16(whA1, Bprev, bc1, 0, 0, 0);

    float mx0 = -1e30f, mx1 = -1e30f, mx2 = -1e30f;
    bmax3(mx0, mx1, mx2, kA0, lh0[0]); bmax3(mx0, mx1, mx2, kA1, lh0[1]);
    bmax3(mx0, mx1, mx2, kA2, lh0[2]); bmax3(mx0, mx1, mx2, kA3, lh0[3]);
    bmax3(mx0, mx1, mx2, kB0, lh1[0]); bmax3(mx0, mx1, mx2, kB1, lh1[1]);
    bmax3(mx0, mx1, mx2, kB2, lh1[2]); bmax3(mx0, mx1, mx2, kB3, lh1[3]);
    mx0 = fmaxf(mx0, __shfl_xor(mx0, 16)); mx0 = fmaxf(mx0, __shfl_xor(mx0, 32));
    mx1 = fmaxf(mx1, __shfl_xor(mx1, 16)); mx1 = fmaxf(mx1, __shfl_xor(mx1, 32));
    mx2 = fmaxf(mx2, __shfl_xor(mx2, 16)); mx2 = fmaxf(mx2, __shfl_xor(mx2, 32));

    float ev0 = __expf(lh0[0] - bsel3(mx0, mx1, mx2, kA0));
    float ev1 = __expf(lh0[1] - bsel3(mx0, mx1, mx2, kA1));
    float ev2 = __expf(lh0[2] - bsel3(mx0, mx1, mx2, kA2));
    float ev3 = __expf(lh0[3] - bsel3(mx0, mx1, mx2, kA3));
    float ev4 = __expf(lh1[0] - bsel3(mx0, mx1, mx2, kB0));
    float ev5 = __expf(lh1[1] - bsel3(mx0, mx1, mx2, kB1));
    float ev6 = __expf(lh1[2] - bsel3(mx0, mx1, mx2, kB2));
    float ev7 = __expf(lh1[3] - bsel3(mx0, mx1, mx2, kB3));
    float s0 = 0.f, s1 = 0.f, s2 = 0.f;
    badd3(s0, s1, s2, kA0, ev0); badd3(s0, s1, s2, kA1, ev1);
    badd3(s0, s1, s2, kA2, ev2); badd3(s0, s1, s2, kA3, ev3);
    badd3(s0, s1, s2, kB0, ev4); badd3(s0, s1, s2, kB1, ev5);
    badd3(s0, s1, s2, kB2, ev6); badd3(s0, s1, s2, kB3, ev7);
    s0 += __shfl_xor(s0, 16); s0 += __shfl_xor(s0, 32);
    s1 += __shfl_xor(s1, 16); s1 += __shfl_xor(s1, 32);
    s2 += __shfl_xor(s2, 16); s2 += __shfl_xor(s2, 32);
    float lse0 = mx0 + __logf(s0);
    float lse1 = mx1 + __logf(s1);
    float lse2 = mx2 + __logf(s2);
    float sc0 = __expf(mx0 - lse0);
    float sc1 = __expf(mx1 - lse1);
    float sc2 = __expf(mx2 - lse2);

    float en0 = 0.f, en1 = 0.f, en2 = 0.f;
    float pl = 1.f;
#define HSLOT(LV, EV, KM, OM) {                                \
      float lse_ = bsel3(lse0, lse1, lse2, KM);                \
      float lp_  = (LV) - lse_;                                \
      float p_   = (EV) * bsel3(sc0, sc1, sc2, KM);            \
      badd3(en0, en1, en2, KM, -p_ * lp_);                     \
      int a_ = bseli3(a0, a1, a2, KM);                         \
      pl = ((OM) == a_) ? pl * lp_ : pl; }
    HSLOT(lh0[0], ev0, kA0, oA0) HSLOT(lh0[1], ev1, kA1, oA1)
    HSLOT(lh0[2], ev2, kA2, oA2) HSLOT(lh0[3], ev3, kA3, oA3)
    HSLOT(lh1[0], ev4, kB0, oB0) HSLOT(lh1[1], ev5, kB1, oB1)
    HSLOT(lh1[2], ev6, kB2, oB2) HSLOT(lh1[3], ev7, kB3, oB3)
#undef HSLOT
    en0 += __shfl_xor(en0, 16); en0 += __shfl_xor(en0, 32);
    en1 += __shfl_xor(en1, 16); en1 += __shfl_xor(en1, 32);
    en2 += __shfl_xor(en2, 16); en2 += __shfl_xor(en2, 32);
    pl  *= __shfl_xor(pl, 16);  pl  *= __shfl_xor(pl, 32);

    if (q == 0) {
      float* ob = out + (size_t)rowG*3;
      ob[0] = (float)a0; ob[1] = (float)a1; ob[2] = (float)a2;   // actions echo
      float* eb = out + OUT_ENT + (size_t)rowG*3;
      eb[0] = en0; eb[1] = en1; eb[2] = en2;                      // entropies
      out[OUT_LP + rowG] = pl;                                    // logprob
    }

    rc0 = rn0; rc1 = rn1; rc2 = rn2; rc3 = rn3;
  }
#undef LOADG
#undef BBUILD
}

extern "C" void kernel_launch(void* const* d_in, const int* in_sizes, int n_in,
                              void* d_out, int out_size, void* d_ws, size_t ws_size,
                              hipStream_t stream)
{
  const float* x       = (const float*)d_in[0];
  const int*   done    = (const int*)  d_in[1];
  const int*   actions = (const int*)  d_in[2];
  const float* W1  = (const float*)d_in[3];
  const float* b1  = (const float*)d_in[4];
  const float* W2  = (const float*)d_in[5];
  const float* b2  = (const float*)d_in[6];
  const float* W3  = (const float*)d_in[7];
  const float* b3  = (const float*)d_in[8];
  const float* Wih = (const float*)d_in[9];
  const float* Whh = (const float*)d_in[10];
  const float* bih = (const float*)d_in[11];
  const float* bhh = (const float*)d_in[12];
  const float* Wh  = (const float*)d_in[13];
  const float* bh  = (const float*)d_in[14];
  const float* h0  = (const float*)d_in[15];
  const float* c0  = (const float*)d_in[16];
  float* out = (float*)d_out;

  uint2* G1q = (uint2*)d_ws;                   // TBA*32 uint2 = 16.8 MB

  mlp_kernel<<<TBA/128, 512, 0, stream>>>(
      x, W1, W2, W3, Wih, b1, b2, b3, bih, bhh, G1q);
  lstm_kernel<<<32 * NCHUNK, 64, 0, stream>>>(
      G1q, Whh, Wh, bh, done, actions, h0, c0, out);
}